// Round 3
// baseline (83.924 us; speedup 1.0000x reference)
//
#include <hip/hip_runtime.h>

// out[b,u] = prod_i ( x[b,i]*w[i,u] + (1 - w[i,u]) ) = prod_i ( 1 + w[i,u]*(x[b,i]-1) )
// B=2048, IN_DIM=256, UNITS=512
//
// Round 9: DIAGNOSTIC build. Rounds 7-8 (pipelining, occupancy 2->4 waves/SIMD)
// each moved the kernel ~4% -- both "overlap" theories failed, and the kernel
// has never been visible in rocprof top-5 (it is faster than the 41us
// workspace-poison fills). This build runs the main product loop REP=2 times
// (pass 0 discarded via asm-volatile sinks, pass 1 is the real result ->
// correctness unchanged) to push the kernel above the fills and capture its
// VALUBusy / VGPR_Count / Occupancy / LDS_BANK_CONFLICT counters.
// Outcome decode:
//   kernel visible ~50us, VALUBusy high  -> inst-count bound (pk emission/spills)
//   kernel visible ~50us, VALUBusy ~25%  -> stall-bound despite 4 waves/SIMD
//   kernel still invisible, dur ~72-76   -> kernel is ~3-5us, harness-floored
// Structure otherwise byte-identical to round 8.

typedef float v2f __attribute__((ext_vector_type(2)));

#define B_DIM   2048
#define IN_DIM  256
#define UNITS   512
#define BT      32      // block tile b
#define UT      64      // block tile u
#define BLOCK   512
#define NSL     16      // i-slices per block
#define KIS     16      // i per slice
#define CHUNK   4       // i per slice per w chunk
#define NCH     4       // chunks (KIS/CHUNK)
#define REP     2       // DIAGNOSTIC: run main loop twice, discard pass 0
#define PSTR    68      // combine plane: per-thread float stride (4-way max)
#define PLANE   (32*PSTR)

#define XS_F    (IN_DIM*32)   // 8192 floats: y = x-1, [i][b]
#define WBUF_F  (64*64)       // 4096 floats per w chunk buffer (64 rows x 64 u)
#define LDS_F   (8*PLANE)     // 17408 >= XS_F + 2*WBUF_F (16384)

__global__ __launch_bounds__(BLOCK, 4) void prodw_kernel(
    const float* __restrict__ x,   // [B, IN_DIM]
    const float* __restrict__ w,   // [IN_DIM, UNITS]
    float* __restrict__ out)       // [B, UNITS]
{
    __shared__ __align__(16) float lds[LDS_F];
    float* __restrict__ xs  = lds;                    // [256][32]
    float* __restrict__ ws0 = lds + XS_F;             // [64][64] chunk buf A
    float* __restrict__ ws1 = lds + XS_F + WBUF_F;    // [64][64] chunk buf B

    const int tid = threadIdx.x;
    const int s   = tid >> 5;        // i-slice 0..15
    const int t   = tid & 31;        // cell-thread 0..31
    const int tb  = t >> 3;          // b-octet 0..3
    const int tu  = t & 7;           // u-octet 0..7
    const int wv  = tid >> 6;        // wave 0..7
    const int ln  = tid & 63;        // lane 0..63
    const int ublk = blockIdx.x * UT;
    const int bblk = blockIdx.y * BT;

    // ---- per-lane prefetch source addresses for w (2 calls/wave/chunk) ----
    const float* wsrc[2];
    int lofs[2];
#pragma unroll
    for (int k = 0; k < 2; ++k) {
        const int seg = wv * 2 + k;
        const int r   = seg * 4 + (ln >> 4);       // 0..63
        const int ss  = r >> 2;                    // slice 0..15
        const int ii  = r & 3;
        const int xr  = (ss & 1) << 2;
        const int col = ((ln & 15) * 4) ^ xr;
        wsrc[k] = w + (size_t)(ss * KIS + ii) * UNITS + ublk + col;
        lofs[k] = seg * 256;                       // wave-uniform
    }

    // ---- issue w chunk 0 into ws0 (async, drains at first barrier) ----
#pragma unroll
    for (int k = 0; k < 2; ++k)
        __builtin_amdgcn_global_load_lds(
            (const __attribute__((address_space(1))) void*)(wsrc[k]),
            (__attribute__((address_space(3))) void*)(ws0 + lofs[k]), 16, 0, 0);

    // ---- stage ALL of x once, transposed, as y = x-1 ----
#pragma unroll
    for (int r = 0; r < 4; ++r) {
        const int idx  = r * BLOCK + tid;          // 0..2047
        const int b    = idx & 31;
        const int srow = idx >> 5;                 // 0..63 (i quad)
        const float4 f = *(const float4*)
            (x + (size_t)(bblk + b) * IN_DIM + srow * 4);
        const int row = srow * 4;
        xs[(row + 0) * 32 + b] = f.x - 1.0f;
        xs[(row + 1) * 32 + b] = f.y - 1.0f;
        xs[(row + 2) * 32 + b] = f.z - 1.0f;
        xs[(row + 3) * 32 + b] = f.w - 1.0f;
    }

    __align__(16) float af[64];      // acc tile [jb][ju]
    v2f* __restrict__ acc = (v2f*)af;

    const int swz = (s & 1) << 2;    // compute-side w col swizzle

#pragma unroll 1
    for (int rep = 0; rep < REP; ++rep) {
        if (rep > 0) {
            // re-issue chunk 0 for this pass (ws0 free: last written c=2,
            // all reads barriered)
#pragma unroll
            for (int k = 0; k < 2; ++k)
                __builtin_amdgcn_global_load_lds(
                    (const __attribute__((address_space(1))) void*)(wsrc[k]),
                    (__attribute__((address_space(3))) void*)(ws0 + lofs[k]),
                    16, 0, 0);
        }

#pragma unroll
        for (int k = 0; k < 32; ++k) acc[k] = (v2f){1.0f, 1.0f};

        __syncthreads();   // x staged + this pass's w chunk0 landed (vmcnt drain)

#pragma unroll
        for (int c = 0; c < NCH; ++c) {
            float* const wcur = (c & 1) ? ws1 : ws0;
            float* const wnxt = (c & 1) ? ws0 : ws1;

            if (c + 1 < NCH) {
                const size_t coff = (size_t)(c + 1) * CHUNK * UNITS;
#pragma unroll
                for (int k = 0; k < 2; ++k)
                    __builtin_amdgcn_global_load_lds(
                        (const __attribute__((address_space(1))) void*)(wsrc[k] + coff),
                        (__attribute__((address_space(3))) void*)(wnxt + lofs[k]),
                        16, 0, 0);
            }

#pragma unroll
            for (int ii = 0; ii < CHUNK; ++ii) {
                const int xrow = s * KIS + c * CHUNK + ii;   // global i
                const int wrow = s * CHUNK + ii;             // row in chunk buf
                const float4 ya = *(const float4*)&xs[xrow * 32 + tb * 8];
                const float4 yb = *(const float4*)&xs[xrow * 32 + tb * 8 + 4];
                const float4 w0 = *(const float4*)&wcur[wrow * 64 + ((tu * 8) ^ swz)];
                const float4 w1 = *(const float4*)&wcur[wrow * 64 + ((tu * 8 + 4) ^ swz)];

                v2f wvv[4] = {{w0.x, w0.y}, {w0.z, w0.w}, {w1.x, w1.y}, {w1.z, w1.w}};
                const float yv[8] = {ya.x, ya.y, ya.z, ya.w, yb.x, yb.y, yb.z, yb.w};

#pragma unroll
                for (int jb = 0; jb < 8; ++jb) {
                    const v2f yy = {yv[jb], yv[jb]};
#pragma unroll
                    for (int q = 0; q < 4; ++q)
                        acc[jb * 4 + q] *= __builtin_elementwise_fma(
                            yy, wvv[q], (v2f){1.0f, 1.0f});
                }
            }
            __syncthreads();   // readers done with wcur; wnxt loads drained
        }

        // discard pass 0 (keep values live so nothing is DCE'd; rule #17)
        if (rep < REP - 1) {
#pragma unroll
            for (int k = 0; k < 32; ++k)
                asm volatile("" :: "v"(acc[k]));
        }
    }

    // ---- binary-tree combine of 16 slice partials through LDS ----
#pragma unroll
    for (int half = NSL / 2; half >= 1; half >>= 1) {
        __syncthreads();
        if (s >= half && s < 2 * half) {
            float* __restrict__ pl = lds + (size_t)(s - half) * PLANE + t * PSTR;
#pragma unroll
            for (int k = 0; k < 16; ++k)
                *(float4*)&pl[k * 4] = ((const float4*)af)[k];
        }
        __syncthreads();
        if (s < half) {
            const float* __restrict__ pl = lds + (size_t)s * PLANE + t * PSTR;
#pragma unroll
            for (int k = 0; k < 16; ++k) {
                const float4 q = *(const float4*)&pl[k * 4];
                float4* a4 = &((float4*)af)[k];
                a4->x *= q.x; a4->y *= q.y; a4->z *= q.z; a4->w *= q.w;
            }
        }
    }

    // ---- slice 0 stores the 32x64 block tile ----
    if (s == 0) {
#pragma unroll
        for (int jb = 0; jb < 8; ++jb) {
            float* __restrict__ po =
                out + (size_t)(bblk + tb * 8 + jb) * UNITS + ublk + tu * 8;
            *(float4*)(po)     = *(const float4*)&af[jb * 8];
            *(float4*)(po + 4) = *(const float4*)&af[jb * 8 + 4];
        }
    }
}

extern "C" void kernel_launch(void* const* d_in, const int* in_sizes, int n_in,
                              void* d_out, int out_size, void* d_ws, size_t ws_size,
                              hipStream_t stream) {
    const float* x = (const float*)d_in[0];        // 2048*256
    const float* w = (const float*)d_in[1];        // 256*512
    float* out     = (float*)d_out;                // 2048*512

    dim3 grid(UNITS / UT, B_DIM / BT);             // (8, 64) = 512 blocks
    prodw_kernel<<<grid, BLOCK, 0, stream>>>(x, w, out);
}

// Round 4
// 71.308 us; speedup vs baseline: 1.1769x; 1.1769x over previous
//
#include <hip/hip_runtime.h>

// out[b,u] = prod_i ( x[b,i]*w[i,u] + (1 - w[i,u]) ) = prod_i ( 1 + w[i,u]*(x[b,i]-1) )
// B=2048, IN_DIM=256, UNITS=512
//
// Round 10: LDS-free main loop via lane=b / scalar-w restructure.
// R9 diagnostic: main loop = 13.4us (2.6x its LDS model); prologue+barriers+
// combine ~= another 13-16us. Root cause: every operand transits per-lane
// ds_read_b128 even though w is shared by all b and x by all u.
// New mapping: wave = 64 lanes = 64 b (lane-private y=x-1 in 16 VGPRs),
// wave-uniform (i,u) => w reads are SCALAR (s_load -> SGPR, feeds
// v_pk_fma_f32 as the one-SGPR-pair operand). Main loop: 64 pk insts/i,
// NO ds_read, NO barriers. 16 waves = 16 i-slices (same i-partition as R8
// -> identical numerics), combine = 4-round XOR-swizzled LDS tree (128KB).
// Grid (8,32)=256 blocks, 1/CU, 4 waves/SIMD via __launch_bounds__(1024,4).

typedef float v2f __attribute__((ext_vector_type(2)));

#define B_DIM   2048
#define IN_DIM  256
#define UNITS   512
#define BT      64      // b per block (= lanes per wave)
#define UT      64      // u per block (all waves same u-tile)
#define BLOCK   1024
#define NW      16      // waves per block = i-slices
#define KIS     16      // i per wave
#define PLANE_F (64*64) // floats per combine plane (16 KB)

__global__ __launch_bounds__(BLOCK, 4) void prodw_kernel(
    const float* __restrict__ x,   // [B, IN_DIM]
    const float* __restrict__ w,   // [IN_DIM, UNITS]
    float* __restrict__ out)       // [B, UNITS]
{
    __shared__ __align__(16) float lds[(NW / 2) * PLANE_F];   // 128 KB

    const int tid  = threadIdx.x;
    const int ln   = tid & 63;                                   // lane = b
    const int wid  = __builtin_amdgcn_readfirstlane(tid >> 6);   // wave = i-slice
    const int ublk = blockIdx.x * UT;
    const int bblk = blockIdx.y * BT;

    // ---- y = x-1 for this lane's b-row, this wave's i-slice (registers) ----
    float yv[KIS];
    {
        const float* xp = x + (size_t)(bblk + ln) * IN_DIM + wid * KIS;
#pragma unroll
        for (int k = 0; k < KIS / 4; ++k) {
            const float4 f = *(const float4*)(xp + 4 * k);
            yv[4 * k + 0] = f.x - 1.0f;
            yv[4 * k + 1] = f.y - 1.0f;
            yv[4 * k + 2] = f.z - 1.0f;
            yv[4 * k + 3] = f.w - 1.0f;
        }
    }

    v2f acc[32];
#pragma unroll
    for (int q = 0; q < 32; ++q) acc[q] = (v2f){1.0f, 1.0f};

    // wave-uniform w row base: all indices derived from readfirstlane/blockIdx
    const float* wp = w + (size_t)(wid * KIS) * UNITS + ublk;

    // ---- main loop: zero LDS, zero barriers ----
#pragma unroll 4
    for (int ii = 0; ii < KIS; ++ii) {
        const float* wr = wp + (size_t)ii * UNITS;   // uniform -> s_load
        const v2f yy = {yv[ii], yv[ii]};
#pragma unroll
        for (int q = 0; q < 32; ++q) {
            const v2f wv = *(const v2f*)(wr + 2 * q);   // wave-uniform 8B
            acc[q] *= __builtin_elementwise_fma(wv, yy, (v2f){1.0f, 1.0f});
        }
    }

    // ---- combine across 16 waves (elementwise product), XOR-swizzled b128 ----
    // lane row = 256B; granule XOR ((ln&7)<<2 floats) spreads 8 consecutive
    // lanes across all 32 banks -> minimal (inherent) b128 serialization.
#pragma unroll
    for (int half = NW / 2; half >= 1; half >>= 1) {
        __syncthreads();
        if (wid >= half && wid < 2 * half) {
            float* pl = lds + (size_t)(wid - half) * PLANE_F + ln * 64;
#pragma unroll
            for (int k = 0; k < 16; ++k)
                *(float4*)&pl[(4 * k) ^ ((ln & 7) << 2)] = ((const float4*)acc)[k];
        }
        __syncthreads();
        if (wid < half) {
            const float* pl = lds + (size_t)wid * PLANE_F + ln * 64;
#pragma unroll
            for (int k = 0; k < 16; ++k) {
                const float4 qv = *(const float4*)&pl[(4 * k) ^ ((ln & 7) << 2)];
                float4* a4 = &((float4*)acc)[k];
                a4->x *= qv.x; a4->y *= qv.y; a4->z *= qv.z; a4->w *= qv.w;
            }
        }
    }

    // ---- wave 0 stores its lane's b-row u-span (256B contiguous per lane) ----
    if (wid == 0) {
        float* po = out + (size_t)(bblk + ln) * UNITS + ublk;
#pragma unroll
        for (int k = 0; k < 16; ++k)
            *(float4*)(po + 4 * k) = ((const float4*)acc)[k];
    }
}

extern "C" void kernel_launch(void* const* d_in, const int* in_sizes, int n_in,
                              void* d_out, int out_size, void* d_ws, size_t ws_size,
                              hipStream_t stream) {
    const float* x = (const float*)d_in[0];        // 2048*256
    const float* w = (const float*)d_in[1];        // 256*512
    float* out     = (float*)d_out;                // 2048*512

    dim3 grid(UNITS / UT, B_DIM / BT);             // (8, 32) = 256 blocks
    prodw_kernel<<<grid, BLOCK, 0, stream>>>(x, w, out);
}